// Round 12
// baseline (608.908 us; speedup 1.0000x reference)
//
#include <hip/hip_runtime.h>
#include <math.h>

// 2-layer ReLU RNN, B=256, T=1000 (input 800 + zero pad), H=128, F=5.
// R12: R9's barrier-free 4-wave dataflow (verified correct at R9) with the
// sync overhead removed. 256 blocks x 256 thr = 4 waves, one per SIMD:
//   w0: h0[s] = relu(Whh0.h0[s-1] + xw[s] + b0)   (in-wave recurrence)
//   w1: A[t]  = Wih1.h0[t] + b1
//   w2: h1[t] = relu(Whh1.h1[t-1] + A[t])          (in-wave recurrence)
//   w3: xw[t] = Wih0.x[t] (24+ ahead) + y[u] in 16-step quad-DPP groups
// R9 ran 668us because of per-step threadfence (full lgkm drain), per-step
// volatile polls (~120cyc LDS latency on the critical path), and a 6-chained
// shfl y-path. Fixes: (1) NO fence - same-wave DS ops are pipe-ordered, a
// compiler barrier suffices before the flag write; (2) publish every 4
// steps; (3) polls cached in registers, spin only when cache insufficient
// (s_sleep(1) in spin); (4) y done 16-at-a-time with quad_perm DPP reduce.
// Rings: h0r/Ar depth 16, h1r 32 (y lags ~20), xwr 32. Backpressure audited:
// all waits are on strictly-earlier pipeline stages or capped at 800.
// Lane layout per matvec wave (R9-verified): qd=l>>2 rows 8qd..+7,
// cc=l&3 cols 32cc..+31; wreg[8][16] h16x2; quad allreduce 0xB1/0x4E.

#define TT    1000
#define TIN   800
#define HD    128
#define NF    5
#define BATCH 256

typedef float f32x4v __attribute__((ext_vector_type(4)));
typedef _Float16 h16x2 __attribute__((ext_vector_type(2)));
typedef _Float16 h16x8 __attribute__((ext_vector_type(8)));

template<int CTRL>
__device__ __forceinline__ float dpp_mov(float v) {
    union { float f; int i; } u, r;
    u.f = v;
    r.i = __builtin_amdgcn_update_dpp(0, u.i, CTRL, 0xF, 0xF, true);
    return r.f;
}

__global__ __launch_bounds__(256, 1) void rnn_pipe2(
    const float* __restrict__ x,        // [256,800,5]
    const float* __restrict__ h_state,  // [2,256,128]
    const float* __restrict__ w_ih0,    // [128,5]
    const float* __restrict__ w_hh0,    // [128,128]
    const float* __restrict__ b_ih0,    // [128]
    const float* __restrict__ b_hh0,    // [128]
    const float* __restrict__ w_ih1,    // [128,128]
    const float* __restrict__ w_hh1,    // [128,128]
    const float* __restrict__ b_ih1,    // [128]
    const float* __restrict__ b_hh1,    // [128]
    const float* __restrict__ w_out,    // [1,128]
    const float* __restrict__ b_out,    // [1]
    float* __restrict__ out)            // [204800 y] ++ [65536 final states]
{
    __shared__ __align__(16) float     x_lds[TIN * 8];   // 25.6 KB
    __shared__ __align__(16) float     xwr[32][HD];      // 16 KB
    __shared__ __align__(16) _Float16  h0r[16][HD];      // 4 KB
    __shared__ __align__(16) _Float16  h1r[32][HD];      // 8 KB
    __shared__ __align__(16) float     Ar[16][HD];       // 8 KB
    __shared__ float y_lds[TIN];                         // 3.2 KB
    __shared__ int   prog[8];   // 0:h0 1:A 2:h1 3:y 4:xw

    const int tid = threadIdx.x;
    const int bb  = blockIdx.x;
    const int wv  = tid >> 6;           // engine 0..3
    const int l   = tid & 63;
    const int qd  = l >> 2;             // rows 8qd..8qd+7
    const int cc  = l & 3;              // cols 32cc..32cc+31

    volatile int* vp = prog;

    if (tid < 8) prog[tid] = 0;
    for (int i = tid; i < TIN * NF; i += 256) {
        int t = i / 5, f = i - 5 * t;
        x_lds[t * 8 + f] = x[bb * (TIN * NF) + i];
    }
    if (tid < HD) {
        h0r[15][tid] = (_Float16)h_state[bb * HD + tid];
        h1r[31][tid] = (_Float16)h_state[BATCH * HD + bb * HD + tid];
    }

    // ---- resident weights ----
    h16x2 wreg[8][16];
    float bias[8];
    if (wv < 3) {
        const float* W = (wv == 0) ? w_hh0 : ((wv == 1) ? w_ih1 : w_hh1);
        #pragma unroll
        for (int j = 0; j < 8; ++j) {
            const float* rp = W + (8 * qd + j) * HD + 32 * cc;
            #pragma unroll
            for (int t = 0; t < 16; ++t) {
                h16x2 w2 = { (_Float16)rp[2 * t], (_Float16)rp[2 * t + 1] };
                wreg[j][t] = w2;
            }
            bias[j] = (wv == 0) ? (b_ih0[8 * qd + j] + b_hh0[8 * qd + j])
                    : (wv == 1) ? (b_ih1[8 * qd + j] + b_hh1[8 * qd + j]) : 0.f;
        }
    }
    float w0a[NF], w0b[NF];
    h16x2 woq[16];
    if (wv == 3) {
        #pragma unroll
        for (int f = 0; f < NF; ++f) {
            w0a[f] = w_ih0[l * NF + f];
            w0b[f] = w_ih0[(l + 64) * NF + f];
        }
        #pragma unroll
        for (int k = 0; k < 16; ++k) {
            woq[k][0] = (_Float16)w_out[(l & 3) * 32 + 2 * k];
            woq[k][1] = (_Float16)w_out[(l & 3) * 32 + 2 * k + 1];
        }
    }
    const float bout = b_out[0];

    __syncthreads();

    // cached poll: only touch LDS when the cached value is insufficient
    #define POLLGE(idx, val, cache) do { if ((cache) < (val)) {            \
        (cache) = vp[idx];                                                 \
        while ((cache) < (val)) { __builtin_amdgcn_s_sleep(1);             \
                                  (cache) = vp[idx]; }                     \
        __asm__ __volatile__("" ::: "memory"); } } while (0)
    // no fence: same-wave DS ops retire in order; block compiler reorder only
    #define PUBLISH(idx, val) do { __asm__ __volatile__("" ::: "memory");  \
        if (l == 0) vp[idx] = (val); } while (0)

    #define TILE_DOTS(HP, ACC) do {                                        \
        h16x8 q0 = *(const h16x8*)(HP);                                    \
        h16x8 q1 = *(const h16x8*)((HP) + 8);                              \
        h16x8 q2 = *(const h16x8*)((HP) + 16);                             \
        h16x8 q3 = *(const h16x8*)((HP) + 24);                             \
        h16x2 hh[16];                                                      \
        _Pragma("unroll")                                                  \
        for (int t = 0; t < 4; ++t) {                                      \
            hh[t]      = (h16x2){ q0[2*t], q0[2*t+1] };                    \
            hh[4 + t]  = (h16x2){ q1[2*t], q1[2*t+1] };                    \
            hh[8 + t]  = (h16x2){ q2[2*t], q2[2*t+1] };                    \
            hh[12 + t] = (h16x2){ q3[2*t], q3[2*t+1] };                    \
        }                                                                  \
        _Pragma("unroll")                                                  \
        for (int j = 0; j < 8; ++j) {                                      \
            float a0 = 0.f;                                                \
            _Pragma("unroll")                                              \
            for (int t = 0; t < 16; ++t)                                   \
                a0 = __builtin_amdgcn_fdot2(wreg[j][t], hh[t], a0, false); \
            ACC[j] = a0;                                                   \
        }                                                                  \
        _Pragma("unroll")                                                  \
        for (int j = 0; j < 8; ++j) ACC[j] += dpp_mov<0xB1>(ACC[j]);       \
        _Pragma("unroll")                                                  \
        for (int j = 0; j < 8; ++j) ACC[j] += dpp_mov<0x4E>(ACC[j]);       \
    } while (0)

    float fin[8];
    #pragma unroll
    for (int j = 0; j < 8; ++j) fin[j] = 0.f;

    if (wv == 0) {
        // ---- w0: h0 recurrence (pacer) ----
        int p1c = 0, p4c = 0;
        for (int s = 0; s < TT; ++s) {
            if (s >= 16 && (s & 3) == 0) POLLGE(1, s - 12, p1c);  // ring bp
            float xw0[8];
            if (s < TIN) {
                POLLGE(4, s + 1, p4c);
                f32x4v a = *(const f32x4v*)&xwr[s & 31][8 * qd];
                f32x4v b = *(const f32x4v*)&xwr[s & 31][8 * qd + 4];
                xw0[0]=a[0]; xw0[1]=a[1]; xw0[2]=a[2]; xw0[3]=a[3];
                xw0[4]=b[0]; xw0[5]=b[1]; xw0[6]=b[2]; xw0[7]=b[3];
            } else {
                #pragma unroll
                for (int j = 0; j < 8; ++j) xw0[j] = 0.f;
            }
            const _Float16* hp = &h0r[(s + 15) & 15][32 * cc];
            float acc[8];
            TILE_DOTS(hp, acc);
            float v[8];
            #pragma unroll
            for (int j = 0; j < 8; ++j)
                v[j] = fmaxf(acc[j] + bias[j] + xw0[j], 0.f);
            if (cc == 0) {
                h16x8 pk;
                #pragma unroll
                for (int j = 0; j < 8; ++j) pk[j] = (_Float16)v[j];
                *(h16x8*)&h0r[s & 15][8 * qd] = pk;
            }
            if (s == TT - 1) {
                #pragma unroll
                for (int j = 0; j < 8; ++j) fin[j] = v[j];
            }
            if ((s & 3) == 3) PUBLISH(0, s + 1);
        }
    } else if (wv == 1) {
        // ---- w1: A[t] = Wih1.h0[t] + b1 ----
        int p0c = 0, p2c = 0;
        for (int t = 0; t < TT; ++t) {
            if (t >= 16 && (t & 3) == 0) POLLGE(2, t - 12, p2c);  // ring bp
            POLLGE(0, t + 1, p0c);
            const _Float16* hp = &h0r[t & 15][32 * cc];
            float acc[8];
            TILE_DOTS(hp, acc);
            if (cc == 0) {
                f32x4v f0 = { acc[0] + bias[0], acc[1] + bias[1],
                              acc[2] + bias[2], acc[3] + bias[3] };
                f32x4v f1 = { acc[4] + bias[4], acc[5] + bias[5],
                              acc[6] + bias[6], acc[7] + bias[7] };
                *(f32x4v*)&Ar[t & 15][8 * qd]     = f0;
                *(f32x4v*)&Ar[t & 15][8 * qd + 4] = f1;
            }
            if ((t & 3) == 3) PUBLISH(1, t + 1);
        }
    } else if (wv == 2) {
        // ---- w2: h1 recurrence ----
        int p1c = 0, p3c = 0;
        for (int t = 0; t < TT; ++t) {
            if (t >= 32 && (t & 3) == 0) {                        // y bp
                int need = t - 28; if (need > TIN) need = TIN;
                POLLGE(3, need, p3c);
            }
            POLLGE(1, t + 1, p1c);
            f32x4v a0 = *(const f32x4v*)&Ar[t & 15][8 * qd];
            f32x4v a1 = *(const f32x4v*)&Ar[t & 15][8 * qd + 4];
            const _Float16* hp = &h1r[(t + 31) & 31][32 * cc];
            float acc[8];
            TILE_DOTS(hp, acc);
            float v[8];
            v[0] = fmaxf(acc[0] + a0[0], 0.f);
            v[1] = fmaxf(acc[1] + a0[1], 0.f);
            v[2] = fmaxf(acc[2] + a0[2], 0.f);
            v[3] = fmaxf(acc[3] + a0[3], 0.f);
            v[4] = fmaxf(acc[4] + a1[0], 0.f);
            v[5] = fmaxf(acc[5] + a1[1], 0.f);
            v[6] = fmaxf(acc[6] + a1[2], 0.f);
            v[7] = fmaxf(acc[7] + a1[3], 0.f);
            if (cc == 0) {
                h16x8 pk;
                #pragma unroll
                for (int j = 0; j < 8; ++j) pk[j] = (_Float16)v[j];
                *(h16x8*)&h1r[t & 31][8 * qd] = pk;
            }
            if (t == TT - 1) {
                #pragma unroll
                for (int j = 0; j < 8; ++j) fin[j] = v[j];
            }
            if ((t & 3) == 3) PUBLISH(2, t + 1);
        }
    } else {
        // ---- w3: xw producer + y groups (16 at a time, quad-DPP) ----
        const int jslot = l >> 2, sub = l & 3;
        int next_y = 0, p0c = 0, p2c = 0;
        #define Y_GROUP(U0) do {                                           \
            const _Float16* hr = &h1r[((U0) + jslot) & 31][sub * 32];      \
            h16x8 g0 = *(const h16x8*)(hr);                                \
            h16x8 g1 = *(const h16x8*)(hr + 8);                            \
            h16x8 g2 = *(const h16x8*)(hr + 16);                           \
            h16x8 g3 = *(const h16x8*)(hr + 24);                           \
            float z = 0.f;                                                 \
            _Pragma("unroll")                                              \
            for (int k = 0; k < 4; ++k) {                                  \
                z = __builtin_amdgcn_fdot2(woq[k],      (h16x2){ g0[2*k], g0[2*k+1] }, z, false); \
                z = __builtin_amdgcn_fdot2(woq[4 + k],  (h16x2){ g1[2*k], g1[2*k+1] }, z, false); \
                z = __builtin_amdgcn_fdot2(woq[8 + k],  (h16x2){ g2[2*k], g2[2*k+1] }, z, false); \
                z = __builtin_amdgcn_fdot2(woq[12 + k], (h16x2){ g3[2*k], g3[2*k+1] }, z, false); \
            }                                                              \
            z += dpp_mov<0xB1>(z);                                         \
            z += dpp_mov<0x4E>(z);                                         \
            if (sub == 0) y_lds[(U0) + jslot] = 1.f / (1.f + expf(-(z + bout))); \
        } while (0)

        for (int tt = 0; tt < TIN; ++tt) {
            if (tt >= 32 && (tt & 7) == 0) POLLGE(0, tt - 24, p0c); // xw bp
            const float* xr = &x_lds[tt * 8];
            f32x4v xv = *(const f32x4v*)xr;
            float x4 = xr[4];
            float xa = w0a[0]*xv[0] + w0a[1]*xv[1] + w0a[2]*xv[2]
                     + w0a[3]*xv[3] + w0a[4]*x4;
            float xb = w0b[0]*xv[0] + w0b[1]*xv[1] + w0b[2]*xv[2]
                     + w0b[3]*xv[3] + w0b[4]*x4;
            xwr[tt & 31][l]      = xa;
            xwr[tt & 31][l + 64] = xb;
            if ((tt & 3) == 3) PUBLISH(4, tt + 1);
            // opportunistic y group (non-blocking - avoids deadlock cycle)
            if ((tt & 7) == 0 && next_y < TIN) {
                if (p2c < next_y + 16) { p2c = vp[2];
                    __asm__ __volatile__("" ::: "memory"); }
                if (p2c >= next_y + 16) {
                    Y_GROUP(next_y);
                    next_y += 16;
                    PUBLISH(3, next_y);
                }
            }
        }
        // drain remaining y groups (blocking is safe now: w2 only needs
        // prog[3] >= min(t-28,800) and we advance to 800 here)
        while (next_y < TIN) {
            POLLGE(2, next_y + 16, p2c);
            Y_GROUP(next_y);
            next_y += 16;
            PUBLISH(3, next_y);
        }
    }

    __syncthreads();

    // ---- epilogue: single global dump ----
    for (int i = tid; i < TIN; i += 256)
        out[bb * TIN + i] = y_lds[i];
    if (wv == 0 && cc == 0) {
        #pragma unroll
        for (int j = 0; j < 8; ++j)
            out[TIN * BATCH + bb * HD + 8 * qd + j] = fin[j];
    }
    if (wv == 2 && cc == 0) {
        #pragma unroll
        for (int j = 0; j < 8; ++j)
            out[TIN * BATCH + BATCH * HD + bb * HD + 8 * qd + j] = fin[j];
    }
}

extern "C" void kernel_launch(void* const* d_in, const int* in_sizes, int n_in,
                              void* d_out, int out_size, void* d_ws, size_t ws_size,
                              hipStream_t stream) {
    (void)in_sizes; (void)n_in; (void)d_ws; (void)ws_size; (void)out_size;
    rnn_pipe2<<<dim3(BATCH), dim3(256), 0, stream>>>(
        (const float*)d_in[0],  (const float*)d_in[1],
        (const float*)d_in[2],  (const float*)d_in[3],
        (const float*)d_in[4],  (const float*)d_in[5],
        (const float*)d_in[6],  (const float*)d_in[7],
        (const float*)d_in[8],  (const float*)d_in[9],
        (const float*)d_in[10], (const float*)d_in[11],
        (float*)d_out);
}